// Round 1
// baseline (11415.021 us; speedup 1.0000x reference)
//
#include <hip/hip_runtime.h>

#define SLEN 400
#define BATCH 32
#define TLEN 16
#define NDEC 15
#define EDIM 128
#define HDIM 256
#define H3 768
#define VVOC 50000
#define VEXT 50020

// ---------- fast math helpers ----------
__device__ __forceinline__ float frcp(float x){ return __builtin_amdgcn_rcpf(x); }
__device__ __forceinline__ float fsig(float x){ return frcp(1.f + __expf(-x)); }
__device__ __forceinline__ float ftanh(float x){
  float e = __expf(2.f*x);
  return 1.f - 2.f*frcp(e + 1.f);
}

__device__ __forceinline__ float wred_max(float v){
  #pragma unroll
  for (int o=32;o>0;o>>=1) v = fmaxf(v, __shfl_down(v,o,64));
  return v;
}
__device__ __forceinline__ float wred_sum(float v){
  #pragma unroll
  for (int o=32;o>0;o>>=1) v += __shfl_down(v,o,64);
  return v;
}
__device__ __forceinline__ float block_max(float v, float* red){
  v = wred_max(v);
  int lane = threadIdx.x & 63, wid = threadIdx.x >> 6;
  if (!lane) red[wid] = v;
  __syncthreads();
  if (threadIdx.x == 0){
    float m = red[0];
    int nw = blockDim.x >> 6;
    for (int w=1;w<nw;++w) m = fmaxf(m, red[w]);
    red[0] = m;
  }
  __syncthreads();
  v = red[0];
  __syncthreads();
  return v;
}
__device__ __forceinline__ float block_sum(float v, float* red){
  v = wred_sum(v);
  int lane = threadIdx.x & 63, wid = threadIdx.x >> 6;
  if (!lane) red[wid] = v;
  __syncthreads();
  if (threadIdx.x == 0){
    float m = red[0];
    int nw = blockDim.x >> 6;
    for (int w=1;w<nw;++w) m += red[w];
    red[0] = m;
  }
  __syncthreads();
  v = red[0];
  __syncthreads();
  return v;
}

// ---------- embedding gather: src sequence (S,B,E) + decoder tokens into cat_all[:,0:128] ----------
__global__ __launch_bounds__(64) void k_embed(
    const int* __restrict__ input_seq, const int* __restrict__ target_seq,
    const float* __restrict__ embedding,
    float* __restrict__ emb_src, float* __restrict__ cat_all)
{
  int row = blockIdx.x;
  int tok; float* dst;
  if (row < SLEN*BATCH) {
    int s = row >> 5, b = row & 31;
    tok = input_seq[b*SLEN + s];
    dst = emb_src + (size_t)row*EDIM;
  } else {
    int rr = row - SLEN*BATCH;
    int t = rr >> 5, b = rr & 31;
    tok = target_seq[b*TLEN + t];       // toks = target_seq[:, :T-1].T
    dst = cat_all + (size_t)rr*896;     // cat cols [0:128) = e
  }
  const float2* src = (const float2*)(embedding + (size_t)tok*EDIM);
  ((float2*)dst)[threadIdx.x] = src[threadIdx.x];
}

// ---------- generic tiled GEMM: C[m,n] = sum_k A[am,k]*W[n,k] + bias[n] ----------
// rev=1 remaps A row m=(s*32+b) -> ((S-1-s)*32+b)   (for backward-direction gi)
#define GBM 128
#define GBN 128
#define GBK 32
__global__ __launch_bounds__(256) void k_gemm(
    const float* __restrict__ A, int lda,
    const float* __restrict__ W, int ldw,
    const float* __restrict__ bias,
    float* __restrict__ C, int ldc,
    int M, int N, int K, int rev)
{
  __shared__ float As[GBK][GBM+4];
  __shared__ float Ws[GBK][GBN+4];
  int tid = threadIdx.x;
  int ty = tid >> 4, tx = tid & 15;
  int m0 = blockIdx.y*GBM, n0 = blockIdx.x*GBN;
  float acc[8][8];
  #pragma unroll
  for (int i=0;i<8;++i)
    #pragma unroll
    for (int jj=0;jj<8;++jj) acc[i][jj] = 0.f;

  for (int k0=0;k0<K;k0+=GBK){
    #pragma unroll
    for (int i=0;i<4;++i){
      int idx = tid + i*256;
      int row = idx >> 3, c4 = idx & 7;
      int m = m0 + row, k = k0 + c4*4;
      float4 v = {0.f,0.f,0.f,0.f};
      if (m < M){
        int am = m;
        if (rev){ int s = m >> 5; am = ((SLEN-1-s)<<5) | (m&31); }
        v = *(const float4*)&A[(size_t)am*lda + k];
      }
      As[c4*4+0][row]=v.x; As[c4*4+1][row]=v.y; As[c4*4+2][row]=v.z; As[c4*4+3][row]=v.w;
    }
    #pragma unroll
    for (int i=0;i<4;++i){
      int idx = tid + i*256;
      int row = idx >> 3, c4 = idx & 7;
      int n = n0 + row, k = k0 + c4*4;
      float4 v = {0.f,0.f,0.f,0.f};
      if (n < N) v = *(const float4*)&W[(size_t)n*ldw + k];
      Ws[c4*4+0][row]=v.x; Ws[c4*4+1][row]=v.y; Ws[c4*4+2][row]=v.z; Ws[c4*4+3][row]=v.w;
    }
    __syncthreads();
    #pragma unroll 4
    for (int kk=0;kk<GBK;++kk){
      float4 a0 = *(const float4*)&As[kk][ty*8];
      float4 a1 = *(const float4*)&As[kk][ty*8+4];
      float4 b0 = *(const float4*)&Ws[kk][tx*8];
      float4 b1 = *(const float4*)&Ws[kk][tx*8+4];
      float av[8]={a0.x,a0.y,a0.z,a0.w,a1.x,a1.y,a1.z,a1.w};
      float bv[8]={b0.x,b0.y,b0.z,b0.w,b1.x,b1.y,b1.z,b1.w};
      #pragma unroll
      for (int i=0;i<8;++i)
        #pragma unroll
        for (int jj=0;jj<8;++jj) acc[i][jj]=fmaf(av[i],bv[jj],acc[i][jj]);
    }
    __syncthreads();
  }
  #pragma unroll
  for (int i=0;i<8;++i){
    int m = m0 + ty*8 + i;
    if (m < M){
      #pragma unroll
      for (int jj=0;jj<8;++jj){
        int n = n0 + tx*8 + jj;
        if (n < N) C[(size_t)m*ldc + n] = acc[i][jj] + bias[n];
      }
    }
  }
}

// ---------- encoder GRU recurrence, both directions; block = (dir,b), thread j owns h[j] ----------
__global__ __launch_bounds__(256) void k_enc(
    const float* __restrict__ gi_f, const float* __restrict__ gi_b,
    const float* __restrict__ Whh_f, const float* __restrict__ bhh_f,
    const float* __restrict__ Whh_b, const float* __restrict__ bhh_b,
    float* __restrict__ enc_states)
{
  int dir = blockIdx.x >> 5, b = blockIdx.x & 31, j = threadIdx.x;
  const float* gi  = dir ? gi_b  : gi_f;
  const float* Whh = dir ? Whh_b : Whh_f;
  const float* bhh = dir ? bhh_b : bhh_f;
  __shared__ float h_s[HDIM];
  h_s[j] = 0.f;
  float bh0 = bhh[j], bh1 = bhh[HDIM+j], bh2 = bhh[2*HDIM+j];
  const float4* w0 = (const float4*)(Whh + (size_t)j*HDIM);
  const float4* w1 = (const float4*)(Whh + (size_t)(HDIM+j)*HDIM);
  const float4* w2 = (const float4*)(Whh + (size_t)(2*HDIM+j)*HDIM);
  float* dst = enc_states + (size_t)b*2*HDIM + dir*HDIM + j;
  __syncthreads();
  for (int s=0;s<SLEN;++s){
    const float* g = gi + ((size_t)s*BATCH + b)*H3;
    float4 A0={0.f,0.f,0.f,0.f}, A1={0.f,0.f,0.f,0.f}, A2={0.f,0.f,0.f,0.f};
    #pragma unroll 8
    for (int k4=0;k4<HDIM/4;++k4){
      float4 h4 = *(const float4*)&h_s[k4*4];
      float4 x0 = w0[k4], x1 = w1[k4], x2 = w2[k4];
      A0.x=fmaf(h4.x,x0.x,A0.x); A0.y=fmaf(h4.y,x0.y,A0.y); A0.z=fmaf(h4.z,x0.z,A0.z); A0.w=fmaf(h4.w,x0.w,A0.w);
      A1.x=fmaf(h4.x,x1.x,A1.x); A1.y=fmaf(h4.y,x1.y,A1.y); A1.z=fmaf(h4.z,x1.z,A1.z); A1.w=fmaf(h4.w,x1.w,A1.w);
      A2.x=fmaf(h4.x,x2.x,A2.x); A2.y=fmaf(h4.y,x2.y,A2.y); A2.z=fmaf(h4.z,x2.z,A2.z); A2.w=fmaf(h4.w,x2.w,A2.w);
    }
    float hr=(A0.x+A0.y)+(A0.z+A0.w)+bh0;
    float hz=(A1.x+A1.y)+(A1.z+A1.w)+bh1;
    float hn=(A2.x+A2.y)+(A2.z+A2.w)+bh2;
    float ir=g[j], iz=g[HDIM+j], inn=g[2*HDIM+j];
    float rr=fsig(ir+hr), zz=fsig(iz+hz);
    float nn=ftanh(inn + rr*hn);
    float hp=h_s[j];
    float h2=nn + zz*(hp-nn);           // (1-z)*n + z*h
    __syncthreads();
    h_s[j]=h2;
    int srow = dir ? (SLEN-1-s) : s;
    dst[(size_t)srow*BATCH*2*HDIM] = h2;
    __syncthreads();
  }
}

// ---------- bridge: h0 = tanh([hf,hb] @ bridge_W.T + b) ----------
__global__ __launch_bounds__(256) void k_bridge(
    const float* __restrict__ enc_states,
    const float* __restrict__ bridge_W, const float* __restrict__ bridge_b,
    float* __restrict__ h_dec)
{
  int b = blockIdx.x, j = threadIdx.x;
  __shared__ float hcat[2*HDIM];
  hcat[j]        = enc_states[((size_t)(SLEN-1)*BATCH + b)*2*HDIM + j];          // forward final
  hcat[HDIM + j] = enc_states[(size_t)b*2*HDIM + HDIM + j];                      // backward final (s=0 slot)
  __syncthreads();
  const float* w = bridge_W + (size_t)j*2*HDIM;
  float4 a = {0.f,0.f,0.f,0.f};
  #pragma unroll 4
  for (int k=0;k<2*HDIM;k+=4){
    float4 h4 = *(const float4*)&hcat[k];
    float4 w4 = *(const float4*)&w[k];
    a.x=fmaf(h4.x,w4.x,a.x); a.y=fmaf(h4.y,w4.y,a.y);
    a.z=fmaf(h4.z,w4.z,a.z); a.w=fmaf(h4.w,w4.w,a.w);
  }
  h_dec[b*HDIM+j] = ftanh((a.x+a.y)+(a.z+a.w) + bridge_b[j]);
}

// ---------- one decoder step: attention + context + GRU (block = batch row) ----------
__global__ __launch_bounds__(256) void k_dec_step(
    int t,
    const float* __restrict__ proj,
    const float* __restrict__ enc_states,
    const float* __restrict__ attn_Wq,
    const float* __restrict__ attn_We,
    const float* __restrict__ dec_Wih,
    const float* __restrict__ dec_Whh,
    const float* __restrict__ dec_bhh,
    const float* __restrict__ gie_all,
    float* __restrict__ h_dec,
    float* __restrict__ alphas_all,
    float* __restrict__ cat_all)
{
  int b = blockIdx.x, j = threadIdx.x;
  __shared__ float h_s[HDIM], q_s[HDIM], we_s[HDIM], ctx_s[2*HDIM], sc[SLEN];
  __shared__ float red[8];
  h_s[j] = h_dec[b*HDIM + j];
  we_s[j] = attn_We[j];
  __syncthreads();
  // q = h @ Wq.T
  {
    const float* wq = attn_Wq + (size_t)j*HDIM;
    float4 a = {0.f,0.f,0.f,0.f};
    #pragma unroll 8
    for (int k=0;k<HDIM;k+=4){
      float4 h4 = *(const float4*)&h_s[k];
      float4 w4 = *(const float4*)&wq[k];
      a.x=fmaf(h4.x,w4.x,a.x); a.y=fmaf(h4.y,w4.y,a.y);
      a.z=fmaf(h4.z,w4.z,a.z); a.w=fmaf(h4.w,w4.w,a.w);
    }
    q_s[j] = (a.x+a.y)+(a.z+a.w);
  }
  __syncthreads();
  // scores[s] = tanh(q + proj[s,b]) . We
  for (int s=j; s<SLEN; s+=256){
    const float* pr = proj + ((size_t)s*BATCH + b)*HDIM;
    float4 a = {0.f,0.f,0.f,0.f};
    #pragma unroll 4
    for (int k=0;k<HDIM;k+=4){
      float4 p4 = *(const float4*)&pr[k];
      float4 q4 = *(const float4*)&q_s[k];
      float4 w4 = *(const float4*)&we_s[k];
      a.x = fmaf(ftanh(q4.x+p4.x), w4.x, a.x);
      a.y = fmaf(ftanh(q4.y+p4.y), w4.y, a.y);
      a.z = fmaf(ftanh(q4.z+p4.z), w4.z, a.z);
      a.w = fmaf(ftanh(q4.w+p4.w), w4.w, a.w);
    }
    sc[s] = (a.x+a.y)+(a.z+a.w);
  }
  __syncthreads();
  // softmax over s
  float m = -1e30f;
  for (int s=j; s<SLEN; s+=256) m = fmaxf(m, sc[s]);
  m = block_max(m, red);
  float ssum = 0.f;
  for (int s=j; s<SLEN; s+=256){ float e = __expf(sc[s]-m); sc[s]=e; ssum+=e; }
  ssum = block_sum(ssum, red);
  float inv = 1.f/ssum;
  for (int s=j; s<SLEN; s+=256){
    float a = sc[s]*inv; sc[s]=a;
    alphas_all[((size_t)t*SLEN + s)*BATCH + b] = a;
  }
  __syncthreads();
  int r = t*BATCH + b;
  // context = sum_s alpha[s] * enc_states[s,b,:]
  for (int d=j; d<2*HDIM; d+=256){
    const float* e0 = enc_states + (size_t)b*2*HDIM + d;
    float a0=0.f,a1=0.f,a2=0.f,a3=0.f;
    #pragma unroll 4
    for (int s=0;s<SLEN;s+=4){
      a0 = fmaf(sc[s+0], e0[(size_t)(s+0)*BATCH*2*HDIM], a0);
      a1 = fmaf(sc[s+1], e0[(size_t)(s+1)*BATCH*2*HDIM], a1);
      a2 = fmaf(sc[s+2], e0[(size_t)(s+2)*BATCH*2*HDIM], a2);
      a3 = fmaf(sc[s+3], e0[(size_t)(s+3)*BATCH*2*HDIM], a3);
    }
    float c = (a0+a1)+(a2+a3);
    ctx_s[d] = c;
    cat_all[(size_t)r*896 + 384 + d] = c;   // cat cols [384:896) = context
  }
  __syncthreads();
  // GRU cell: x = [e, context]; e-part (incl. bih) precomputed in gie_all
  float g[3], hh[3];
  #pragma unroll
  for (int gg=0; gg<3; ++gg){
    int jj = gg*HDIM + j;
    const float* wi = dec_Wih + (size_t)jj*640 + 128;   // ctx columns
    float4 a = {0.f,0.f,0.f,0.f};
    #pragma unroll 4
    for (int k=0;k<2*HDIM;k+=4){
      float4 c4 = *(const float4*)&ctx_s[k];
      float4 w4 = *(const float4*)&wi[k];
      a.x=fmaf(c4.x,w4.x,a.x); a.y=fmaf(c4.y,w4.y,a.y);
      a.z=fmaf(c4.z,w4.z,a.z); a.w=fmaf(c4.w,w4.w,a.w);
    }
    g[gg] = gie_all[(size_t)r*H3 + jj] + (a.x+a.y)+(a.z+a.w);
    const float* wh = dec_Whh + (size_t)jj*HDIM;
    float4 h4a = {0.f,0.f,0.f,0.f};
    #pragma unroll 4
    for (int k=0;k<HDIM;k+=4){
      float4 h4 = *(const float4*)&h_s[k];
      float4 w4 = *(const float4*)&wh[k];
      h4a.x=fmaf(h4.x,w4.x,h4a.x); h4a.y=fmaf(h4.y,w4.y,h4a.y);
      h4a.z=fmaf(h4.z,w4.z,h4a.z); h4a.w=fmaf(h4.w,w4.w,h4a.w);
    }
    hh[gg] = dec_bhh[jj] + (h4a.x+h4a.y)+(h4a.z+h4a.w);
  }
  float rr = fsig(g[0]+hh[0]);
  float zz = fsig(g[1]+hh[1]);
  float nn = ftanh(g[2] + rr*hh[2]);
  float h2 = nn + zz*(h_s[j]-nn);
  h_dec[b*HDIM + j] = h2;
  cat_all[(size_t)r*896 + 128 + j] = h2;    // cat cols [128:384) = h2
}

// ---------- p_gen = sigmoid(cat . pgen_W + b) ----------
__global__ __launch_bounds__(64) void k_pgen(
    const float* __restrict__ cat_all,
    const float* __restrict__ pgen_W, const float* __restrict__ pgen_b,
    float* __restrict__ pgen_all)
{
  int r = blockIdx.x;
  const float* c = cat_all + (size_t)r*896;
  float acc = 0.f;
  for (int k=threadIdx.x; k<896; k+=64) acc = fmaf(c[k], pgen_W[k], acc);
  acc = wred_sum(acc);
  if (threadIdx.x==0) pgen_all[r] = fsig(acc + pgen_b[0]);
}

// ---------- per-row softmax stats over V ----------
__global__ __launch_bounds__(256) void k_rowred(
    const float* __restrict__ logits,
    float* __restrict__ row_max, float* __restrict__ row_sum)
{
  int r = blockIdx.x;
  const float4* row = (const float4*)(logits + (size_t)r*VVOC);
  __shared__ float red[8];
  float m = -1e30f;
  for (int v=threadIdx.x; v<VVOC/4; v+=256){
    float4 x = row[v];
    m = fmaxf(m, fmaxf(fmaxf(x.x,x.y), fmaxf(x.z,x.w)));
  }
  m = block_max(m, red);
  float s = 0.f;
  for (int v=threadIdx.x; v<VVOC/4; v+=256){
    float4 x = row[v];
    s += __expf(x.x-m) + __expf(x.y-m) + __expf(x.z-m) + __expf(x.w-m);
  }
  s = block_sum(s, red);
  if (threadIdx.x==0){ row_max[r]=m; row_sum[r]=1.f/s; }
}

// ---------- write ext (linear domain) for all (t,b,v); t=0 row = 0 ----------
__global__ __launch_bounds__(256) void k_final(
    const float* __restrict__ logits, const float* __restrict__ pgen_all,
    const float* __restrict__ row_max, const float* __restrict__ row_sum,
    float* __restrict__ out)
{
  int v = blockIdx.x*256 + threadIdx.x;
  if (v >= VEXT) return;
  int b = blockIdx.y, t = blockIdx.z;
  size_t o = ((size_t)t*BATCH + b)*VEXT + v;
  if (t == 0){ out[o] = 0.f; return; }
  int r = (t-1)*BATCH + b;
  float val = 1e-12f;
  if (v < VVOC)
    val += pgen_all[r] * row_sum[r] * __expf(logits[(size_t)r*VVOC + v] - row_max[r]);
  out[o] = val;
}

// ---------- scatter copy-distribution ----------
__global__ __launch_bounds__(512) void k_scatter(
    const int* __restrict__ input_seq_ext,
    const float* __restrict__ alphas, const float* __restrict__ pgen_all,
    float* __restrict__ out)
{
  int r = blockIdx.x;               // t*32+b
  int s = threadIdx.x;
  if (s >= SLEN) return;
  int t = r >> 5, b = r & 31;
  float w = (1.f - pgen_all[r]) * alphas[((size_t)t*SLEN + s)*BATCH + b];
  int idx = input_seq_ext[b*SLEN + s];
  atomicAdd(&out[((size_t)(t+1)*BATCH + b)*VEXT + idx], w);
}

// ---------- log transform rows t>=1 ----------
__global__ __launch_bounds__(256) void k_log(float* __restrict__ out)
{
  int v = blockIdx.x*256 + threadIdx.x;
  if (v >= VEXT) return;
  int b = blockIdx.y, t = blockIdx.z + 1;
  size_t o = ((size_t)t*BATCH + b)*VEXT + v;
  out[o] = __logf(out[o]);
}

extern "C" void kernel_launch(void* const* d_in, const int* in_sizes, int n_in,
                              void* d_out, int out_size, void* d_ws, size_t ws_size,
                              hipStream_t stream)
{
  (void)in_sizes; (void)n_in; (void)out_size; (void)ws_size;
  const int*   input_seq     = (const int*)d_in[0];
  const int*   input_seq_ext = (const int*)d_in[1];
  const int*   target_seq    = (const int*)d_in[2];
  const float* embedding     = (const float*)d_in[3];
  const float* enc_Wih_f     = (const float*)d_in[4];
  const float* enc_Whh_f     = (const float*)d_in[5];
  const float* enc_bih_f     = (const float*)d_in[6];
  const float* enc_bhh_f     = (const float*)d_in[7];
  const float* enc_Wih_b     = (const float*)d_in[8];
  const float* enc_Whh_b     = (const float*)d_in[9];
  const float* enc_bih_b     = (const float*)d_in[10];
  const float* enc_bhh_b     = (const float*)d_in[11];
  const float* proj_W        = (const float*)d_in[12];
  const float* proj_b        = (const float*)d_in[13];
  const float* bridge_W      = (const float*)d_in[14];
  const float* bridge_b      = (const float*)d_in[15];
  const float* dec_Wih       = (const float*)d_in[16];
  const float* dec_Whh       = (const float*)d_in[17];
  const float* dec_bih       = (const float*)d_in[18];
  const float* dec_bhh       = (const float*)d_in[19];
  const float* attn_Wq       = (const float*)d_in[20];
  const float* attn_We       = (const float*)d_in[21];
  const float* lin_W         = (const float*)d_in[22];
  const float* lin_b         = (const float*)d_in[23];
  const float* pgen_W        = (const float*)d_in[24];
  const float* pgen_b        = (const float*)d_in[25];
  const float* out_W         = (const float*)d_in[26];
  const float* out_b         = (const float*)d_in[27];
  float* out = (float*)d_out;
  float* ws  = (float*)d_ws;

  // workspace layout (floats); logits overlaps dead gi_f/gi_b region
  float* emb_src    = ws;                    // 1,638,400
  float* enc_states = ws + 1638400;          // 6,553,600
  float* proj       = ws + 8192000;          // 3,276,800
  float* gi_f       = ws + 11468800;         // 9,830,400
  float* gi_b       = ws + 11468800 + 9830400;
  float* logits     = ws + 11468800;         // 24,000,000 (reuses gi region)
  float* cat_all    = ws + 35468800;         // 480*896
  float* gie_all    = ws + 35898880;         // 480*768
  float* h_dec      = ws + 36267520;         // 32*256
  float* alphas     = ws + 36275712;         // 15*400*32
  float* lin_out    = ws + 36467712;         // 480*256
  float* pgen_all   = ws + 36590592;         // 480
  float* row_max    = ws + 36591072;         // 480
  float* row_sum    = ws + 36591552;         // 480
  // total ≈ 146.4 MB

  k_embed<<<dim3(SLEN*BATCH + NDEC*BATCH), dim3(64), 0, stream>>>(
      input_seq, target_seq, embedding, emb_src, cat_all);

  // gi = emb @ Wih.T + bih, both directions (backward uses reversed source rows)
  k_gemm<<<dim3(6,100), dim3(256), 0, stream>>>(emb_src, EDIM, enc_Wih_f, EDIM, enc_bih_f, gi_f, H3, SLEN*BATCH, H3, EDIM, 0);
  k_gemm<<<dim3(6,100), dim3(256), 0, stream>>>(emb_src, EDIM, enc_Wih_b, EDIM, enc_bih_b, gi_b, H3, SLEN*BATCH, H3, EDIM, 1);

  k_enc<<<dim3(64), dim3(256), 0, stream>>>(gi_f, gi_b, enc_Whh_f, enc_bhh_f, enc_Whh_b, enc_bhh_b, enc_states);

  // proj = enc_states @ proj_W.T + proj_b
  k_gemm<<<dim3(2,100), dim3(256), 0, stream>>>(enc_states, 2*HDIM, proj_W, 2*HDIM, proj_b, proj, HDIM, SLEN*BATCH, HDIM, 2*HDIM, 0);

  k_bridge<<<dim3(BATCH), dim3(256), 0, stream>>>(enc_states, bridge_W, bridge_b, h_dec);

  // decoder-embedding part of GRU input gates (incl. dec_bih), batched over all t
  k_gemm<<<dim3(6,4), dim3(256), 0, stream>>>(cat_all, 896, dec_Wih, 640, dec_bih, gie_all, H3, NDEC*BATCH, H3, EDIM, 0);

  for (int t=0;t<NDEC;++t)
    k_dec_step<<<dim3(BATCH), dim3(256), 0, stream>>>(t, proj, enc_states, attn_Wq, attn_We,
        dec_Wih, dec_Whh, dec_bhh, gie_all, h_dec, alphas, cat_all);

  // batched epilogue over all 15 steps
  k_gemm<<<dim3(2,4), dim3(256), 0, stream>>>(cat_all, 896, lin_W, 896, lin_b, lin_out, HDIM, NDEC*BATCH, HDIM, 896, 0);
  k_pgen<<<dim3(NDEC*BATCH), dim3(64), 0, stream>>>(cat_all, pgen_W, pgen_b, pgen_all);
  k_gemm<<<dim3(391,4), dim3(256), 0, stream>>>(lin_out, HDIM, out_W, HDIM, out_b, logits, VVOC, NDEC*BATCH, VVOC, HDIM, 0);
  k_rowred<<<dim3(NDEC*BATCH), dim3(256), 0, stream>>>(logits, row_max, row_sum);
  k_final<<<dim3(196, BATCH, TLEN), dim3(256), 0, stream>>>(logits, pgen_all, row_max, row_sum, out);
  k_scatter<<<dim3(NDEC*BATCH), dim3(512), 0, stream>>>(input_seq_ext, alphas, pgen_all, out);
  k_log<<<dim3(196, BATCH, NDEC), dim3(256), 0, stream>>>(out);
}

// Round 2
// 6648.412 us; speedup vs baseline: 1.7170x; 1.7170x over previous
//
#include <hip/hip_runtime.h>

#define SLEN 400
#define BATCH 32
#define TLEN 16
#define NDEC 15
#define EDIM 128
#define HDIM 256
#define H3 768
#define VVOC 50000
#define VEXT 50020

// ---------- fast math helpers ----------
__device__ __forceinline__ float frcp(float x){ return __builtin_amdgcn_rcpf(x); }
__device__ __forceinline__ float fsig(float x){ return frcp(1.f + __expf(-x)); }
__device__ __forceinline__ float ftanh(float x){
  float e = __expf(2.f*x);
  return 1.f - 2.f*frcp(e + 1.f);
}

__device__ __forceinline__ float wred_max(float v){
  #pragma unroll
  for (int o=32;o>0;o>>=1) v = fmaxf(v, __shfl_down(v,o,64));
  return v;
}
__device__ __forceinline__ float wred_sum(float v){
  #pragma unroll
  for (int o=32;o>0;o>>=1) v += __shfl_down(v,o,64);
  return v;
}
__device__ __forceinline__ float block_max(float v, float* red){
  v = wred_max(v);
  int lane = threadIdx.x & 63, wid = threadIdx.x >> 6;
  if (!lane) red[wid] = v;
  __syncthreads();
  if (threadIdx.x == 0){
    float m = red[0];
    int nw = blockDim.x >> 6;
    for (int w=1;w<nw;++w) m = fmaxf(m, red[w]);
    red[0] = m;
  }
  __syncthreads();
  v = red[0];
  __syncthreads();
  return v;
}
__device__ __forceinline__ float block_sum(float v, float* red){
  v = wred_sum(v);
  int lane = threadIdx.x & 63, wid = threadIdx.x >> 6;
  if (!lane) red[wid] = v;
  __syncthreads();
  if (threadIdx.x == 0){
    float m = red[0];
    int nw = blockDim.x >> 6;
    for (int w=1;w<nw;++w) m += red[w];
    red[0] = m;
  }
  __syncthreads();
  v = red[0];
  __syncthreads();
  return v;
}

// ---------- embedding gather: src sequence (S,B,E) + decoder tokens into cat_all[:,0:128] ----------
__global__ __launch_bounds__(64) void k_embed(
    const int* __restrict__ input_seq, const int* __restrict__ target_seq,
    const float* __restrict__ embedding,
    float* __restrict__ emb_src, float* __restrict__ cat_all)
{
  int row = blockIdx.x;
  int tok; float* dst;
  if (row < SLEN*BATCH) {
    int s = row >> 5, b = row & 31;
    tok = input_seq[b*SLEN + s];
    dst = emb_src + (size_t)row*EDIM;
  } else {
    int rr = row - SLEN*BATCH;
    int t = rr >> 5, b = rr & 31;
    tok = target_seq[b*TLEN + t];       // toks = target_seq[:, :T-1].T
    dst = cat_all + (size_t)rr*896;     // cat cols [0:128) = e
  }
  const float2* src = (const float2*)(embedding + (size_t)tok*EDIM);
  ((float2*)dst)[threadIdx.x] = src[threadIdx.x];
}

// ---------- generic tiled GEMM: C[m,n] = sum_k A[am,k]*W[n,k] + bias[n] ----------
// rev=1 remaps A row m=(s*32+b) -> ((S-1-s)*32+b)   (for backward-direction gi)
#define GBM 128
#define GBN 128
#define GBK 32
__global__ __launch_bounds__(256) void k_gemm(
    const float* __restrict__ A, int lda,
    const float* __restrict__ W, int ldw,
    const float* __restrict__ bias,
    float* __restrict__ C, int ldc,
    int M, int N, int K, int rev)
{
  __shared__ float As[GBK][GBM+4];
  __shared__ float Ws[GBK][GBN+4];
  int tid = threadIdx.x;
  int ty = tid >> 4, tx = tid & 15;
  int m0 = blockIdx.y*GBM, n0 = blockIdx.x*GBN;
  float acc[8][8];
  #pragma unroll
  for (int i=0;i<8;++i)
    #pragma unroll
    for (int jj=0;jj<8;++jj) acc[i][jj] = 0.f;

  for (int k0=0;k0<K;k0+=GBK){
    #pragma unroll
    for (int i=0;i<4;++i){
      int idx = tid + i*256;
      int row = idx >> 3, c4 = idx & 7;
      int m = m0 + row, k = k0 + c4*4;
      float4 v = {0.f,0.f,0.f,0.f};
      if (m < M){
        int am = m;
        if (rev){ int s = m >> 5; am = ((SLEN-1-s)<<5) | (m&31); }
        v = *(const float4*)&A[(size_t)am*lda + k];
      }
      As[c4*4+0][row]=v.x; As[c4*4+1][row]=v.y; As[c4*4+2][row]=v.z; As[c4*4+3][row]=v.w;
    }
    #pragma unroll
    for (int i=0;i<4;++i){
      int idx = tid + i*256;
      int row = idx >> 3, c4 = idx & 7;
      int n = n0 + row, k = k0 + c4*4;
      float4 v = {0.f,0.f,0.f,0.f};
      if (n < N) v = *(const float4*)&W[(size_t)n*ldw + k];
      Ws[c4*4+0][row]=v.x; Ws[c4*4+1][row]=v.y; Ws[c4*4+2][row]=v.z; Ws[c4*4+3][row]=v.w;
    }
    __syncthreads();
    #pragma unroll 4
    for (int kk=0;kk<GBK;++kk){
      float4 a0 = *(const float4*)&As[kk][ty*8];
      float4 a1 = *(const float4*)&As[kk][ty*8+4];
      float4 b0 = *(const float4*)&Ws[kk][tx*8];
      float4 b1 = *(const float4*)&Ws[kk][tx*8+4];
      float av[8]={a0.x,a0.y,a0.z,a0.w,a1.x,a1.y,a1.z,a1.w};
      float bv[8]={b0.x,b0.y,b0.z,b0.w,b1.x,b1.y,b1.z,b1.w};
      #pragma unroll
      for (int i=0;i<8;++i)
        #pragma unroll
        for (int jj=0;jj<8;++jj) acc[i][jj]=fmaf(av[i],bv[jj],acc[i][jj]);
    }
    __syncthreads();
  }
  #pragma unroll
  for (int i=0;i<8;++i){
    int m = m0 + ty*8 + i;
    if (m < M){
      #pragma unroll
      for (int jj=0;jj<8;++jj){
        int n = n0 + tx*8 + jj;
        if (n < N) C[(size_t)m*ldc + n] = acc[i][jj] + bias[n];
      }
    }
  }
}

// ---------- encoder GRU recurrence, persistent weights in registers ----------
// block = (dir, b), 1024 threads = 16 waves. Thread (j, slice): j=tid&255 owns
// output element j of each gate; slice=tid>>8 owns k-columns [slice*64, slice*64+64).
// Weights (3 gates x 64 k) = 192 floats live in VGPRs for the whole 400-step loop.
__global__ __launch_bounds__(1024) void k_enc(
    const float* __restrict__ gi_f, const float* __restrict__ gi_b,
    const float* __restrict__ Whh_f, const float* __restrict__ bhh_f,
    const float* __restrict__ Whh_b, const float* __restrict__ bhh_b,
    float* __restrict__ enc_states)
{
  int dir = blockIdx.x >> 5, b = blockIdx.x & 31;
  int tid = threadIdx.x;
  int j = tid & 255;
  int slice = tid >> 8;          // wave-uniform
  int k0 = slice * 64;
  const float* gi  = dir ? gi_b  : gi_f;
  const float* Whh = dir ? Whh_b : Whh_f;
  const float* bhh = dir ? bhh_b : bhh_f;

  __shared__ float h_s[HDIM];
  __shared__ float pr[3][4][HDIM];     // k-slice partials (12 KB)

  // persistent weights -> registers
  float w[3][64];
  #pragma unroll
  for (int g=0; g<3; ++g){
    const float4* src = (const float4*)(Whh + (size_t)(g*HDIM + j)*HDIM + k0);
    #pragma unroll
    for (int k4=0;k4<16;++k4){
      float4 v = src[k4];
      w[g][4*k4+0]=v.x; w[g][4*k4+1]=v.y; w[g][4*k4+2]=v.z; w[g][4*k4+3]=v.w;
    }
  }
  float bh0 = bhh[j], bh1 = bhh[HDIM+j], bh2 = bhh[2*HDIM+j];
  if (tid < HDIM) h_s[tid] = 0.f;
  float* dst = enc_states + (size_t)b*2*HDIM + dir*HDIM + j;
  __syncthreads();

  for (int s=0;s<SLEN;++s){
    // prefetch this step's input gates (only slice-0 waves need them)
    float ir=0.f, iz=0.f, inn=0.f;
    if (slice == 0){
      const float* g = gi + ((size_t)s*BATCH + b)*H3;
      ir = g[j]; iz = g[HDIM+j]; inn = g[2*HDIM+j];
    }
    // partial dots: h broadcast-read from LDS, weights from registers
    float a0=0.f, a1=0.f, a2=0.f;
    const float4* h4p = (const float4*)&h_s[k0];
    #pragma unroll
    for (int k4=0;k4<16;++k4){
      float4 h4 = h4p[k4];
      a0=fmaf(w[0][4*k4+0],h4.x,a0); a0=fmaf(w[0][4*k4+1],h4.y,a0);
      a0=fmaf(w[0][4*k4+2],h4.z,a0); a0=fmaf(w[0][4*k4+3],h4.w,a0);
      a1=fmaf(w[1][4*k4+0],h4.x,a1); a1=fmaf(w[1][4*k4+1],h4.y,a1);
      a1=fmaf(w[1][4*k4+2],h4.z,a1); a1=fmaf(w[1][4*k4+3],h4.w,a1);
      a2=fmaf(w[2][4*k4+0],h4.x,a2); a2=fmaf(w[2][4*k4+1],h4.y,a2);
      a2=fmaf(w[2][4*k4+2],h4.z,a2); a2=fmaf(w[2][4*k4+3],h4.w,a2);
    }
    pr[0][slice][j]=a0; pr[1][slice][j]=a1; pr[2][slice][j]=a2;
    __syncthreads();
    if (slice == 0){
      float hr = ((pr[0][0][j]+pr[0][1][j])+(pr[0][2][j]+pr[0][3][j]))+bh0;
      float hz = ((pr[1][0][j]+pr[1][1][j])+(pr[1][2][j]+pr[1][3][j]))+bh1;
      float hn = ((pr[2][0][j]+pr[2][1][j])+(pr[2][2][j]+pr[2][3][j]))+bh2;
      float rr = fsig(ir+hr), zz = fsig(iz+hz);
      float nn = ftanh(inn + rr*hn);
      float hp = h_s[j];
      float h2 = nn + zz*(hp-nn);       // (1-z)*n + z*h
      h_s[j] = h2;
      int srow = dir ? (SLEN-1-s) : s;
      dst[(size_t)srow*BATCH*2*HDIM] = h2;
    }
    __syncthreads();
  }
}

// ---------- bridge: h0 = tanh([hf,hb] @ bridge_W.T + b) ----------
__global__ __launch_bounds__(256) void k_bridge(
    const float* __restrict__ enc_states,
    const float* __restrict__ bridge_W, const float* __restrict__ bridge_b,
    float* __restrict__ h_dec)
{
  int b = blockIdx.x, j = threadIdx.x;
  __shared__ float hcat[2*HDIM];
  hcat[j]        = enc_states[((size_t)(SLEN-1)*BATCH + b)*2*HDIM + j];          // forward final
  hcat[HDIM + j] = enc_states[(size_t)b*2*HDIM + HDIM + j];                      // backward final (s=0 slot)
  __syncthreads();
  const float* w = bridge_W + (size_t)j*2*HDIM;
  float4 a = {0.f,0.f,0.f,0.f};
  #pragma unroll 4
  for (int k=0;k<2*HDIM;k+=4){
    float4 h4 = *(const float4*)&hcat[k];
    float4 w4 = *(const float4*)&w[k];
    a.x=fmaf(h4.x,w4.x,a.x); a.y=fmaf(h4.y,w4.y,a.y);
    a.z=fmaf(h4.z,w4.z,a.z); a.w=fmaf(h4.w,w4.w,a.w);
  }
  h_dec[b*HDIM+j] = ftanh((a.x+a.y)+(a.z+a.w) + bridge_b[j]);
}

// ---------- one decoder step: attention + context + GRU (block = batch row) ----------
__global__ __launch_bounds__(256) void k_dec_step(
    int t,
    const float* __restrict__ proj,
    const float* __restrict__ enc_states,
    const float* __restrict__ attn_Wq,
    const float* __restrict__ attn_We,
    const float* __restrict__ dec_Wih,
    const float* __restrict__ dec_Whh,
    const float* __restrict__ dec_bhh,
    const float* __restrict__ gie_all,
    float* __restrict__ h_dec,
    float* __restrict__ alphas_all,
    float* __restrict__ cat_all)
{
  int b = blockIdx.x, j = threadIdx.x;
  __shared__ float h_s[HDIM], q_s[HDIM], we_s[HDIM], ctx_s[2*HDIM], sc[SLEN];
  __shared__ float red[8];
  h_s[j] = h_dec[b*HDIM + j];
  we_s[j] = attn_We[j];
  __syncthreads();
  // q = h @ Wq.T
  {
    const float* wq = attn_Wq + (size_t)j*HDIM;
    float4 a = {0.f,0.f,0.f,0.f};
    #pragma unroll 8
    for (int k=0;k<HDIM;k+=4){
      float4 h4 = *(const float4*)&h_s[k];
      float4 w4 = *(const float4*)&wq[k];
      a.x=fmaf(h4.x,w4.x,a.x); a.y=fmaf(h4.y,w4.y,a.y);
      a.z=fmaf(h4.z,w4.z,a.z); a.w=fmaf(h4.w,w4.w,a.w);
    }
    q_s[j] = (a.x+a.y)+(a.z+a.w);
  }
  __syncthreads();
  // scores[s] = tanh(q + proj[s,b]) . We
  for (int s=j; s<SLEN; s+=256){
    const float* pr = proj + ((size_t)s*BATCH + b)*HDIM;
    float4 a = {0.f,0.f,0.f,0.f};
    #pragma unroll 4
    for (int k=0;k<HDIM;k+=4){
      float4 p4 = *(const float4*)&pr[k];
      float4 q4 = *(const float4*)&q_s[k];
      float4 w4 = *(const float4*)&we_s[k];
      a.x = fmaf(ftanh(q4.x+p4.x), w4.x, a.x);
      a.y = fmaf(ftanh(q4.y+p4.y), w4.y, a.y);
      a.z = fmaf(ftanh(q4.z+p4.z), w4.z, a.z);
      a.w = fmaf(ftanh(q4.w+p4.w), w4.w, a.w);
    }
    sc[s] = (a.x+a.y)+(a.z+a.w);
  }
  __syncthreads();
  // softmax over s
  float m = -1e30f;
  for (int s=j; s<SLEN; s+=256) m = fmaxf(m, sc[s]);
  m = block_max(m, red);
  float ssum = 0.f;
  for (int s=j; s<SLEN; s+=256){ float e = __expf(sc[s]-m); sc[s]=e; ssum+=e; }
  ssum = block_sum(ssum, red);
  float inv = 1.f/ssum;
  for (int s=j; s<SLEN; s+=256){
    float a = sc[s]*inv; sc[s]=a;
    alphas_all[((size_t)t*SLEN + s)*BATCH + b] = a;
  }
  __syncthreads();
  int r = t*BATCH + b;
  // context = sum_s alpha[s] * enc_states[s,b,:]
  for (int d=j; d<2*HDIM; d+=256){
    const float* e0 = enc_states + (size_t)b*2*HDIM + d;
    float a0=0.f,a1=0.f,a2=0.f,a3=0.f;
    #pragma unroll 4
    for (int s=0;s<SLEN;s+=4){
      a0 = fmaf(sc[s+0], e0[(size_t)(s+0)*BATCH*2*HDIM], a0);
      a1 = fmaf(sc[s+1], e0[(size_t)(s+1)*BATCH*2*HDIM], a1);
      a2 = fmaf(sc[s+2], e0[(size_t)(s+2)*BATCH*2*HDIM], a2);
      a3 = fmaf(sc[s+3], e0[(size_t)(s+3)*BATCH*2*HDIM], a3);
    }
    float c = (a0+a1)+(a2+a3);
    ctx_s[d] = c;
    cat_all[(size_t)r*896 + 384 + d] = c;   // cat cols [384:896) = context
  }
  __syncthreads();
  // GRU cell: x = [e, context]; e-part (incl. bih) precomputed in gie_all
  float g[3], hh[3];
  #pragma unroll
  for (int gg=0; gg<3; ++gg){
    int jj = gg*HDIM + j;
    const float* wi = dec_Wih + (size_t)jj*640 + 128;   // ctx columns
    float4 a = {0.f,0.f,0.f,0.f};
    #pragma unroll 4
    for (int k=0;k<2*HDIM;k+=4){
      float4 c4 = *(const float4*)&ctx_s[k];
      float4 w4 = *(const float4*)&wi[k];
      a.x=fmaf(c4.x,w4.x,a.x); a.y=fmaf(c4.y,w4.y,a.y);
      a.z=fmaf(c4.z,w4.z,a.z); a.w=fmaf(c4.w,w4.w,a.w);
    }
    g[gg] = gie_all[(size_t)r*H3 + jj] + (a.x+a.y)+(a.z+a.w);
    const float* wh = dec_Whh + (size_t)jj*HDIM;
    float4 h4a = {0.f,0.f,0.f,0.f};
    #pragma unroll 4
    for (int k=0;k<HDIM;k+=4){
      float4 h4 = *(const float4*)&h_s[k];
      float4 w4 = *(const float4*)&wh[k];
      h4a.x=fmaf(h4.x,w4.x,h4a.x); h4a.y=fmaf(h4.y,w4.y,h4a.y);
      h4a.z=fmaf(h4.z,w4.z,h4a.z); h4a.w=fmaf(h4.w,w4.w,h4a.w);
    }
    hh[gg] = dec_bhh[jj] + (h4a.x+h4a.y)+(h4a.z+h4a.w);
  }
  float rr = fsig(g[0]+hh[0]);
  float zz = fsig(g[1]+hh[1]);
  float nn = ftanh(g[2] + rr*hh[2]);
  float h2 = nn + zz*(h_s[j]-nn);
  h_dec[b*HDIM + j] = h2;
  cat_all[(size_t)r*896 + 128 + j] = h2;    // cat cols [128:384) = h2
}

// ---------- p_gen = sigmoid(cat . pgen_W + b) ----------
__global__ __launch_bounds__(64) void k_pgen(
    const float* __restrict__ cat_all,
    const float* __restrict__ pgen_W, const float* __restrict__ pgen_b,
    float* __restrict__ pgen_all)
{
  int r = blockIdx.x;
  const float* c = cat_all + (size_t)r*896;
  float acc = 0.f;
  for (int k=threadIdx.x; k<896; k+=64) acc = fmaf(c[k], pgen_W[k], acc);
  acc = wred_sum(acc);
  if (threadIdx.x==0) pgen_all[r] = fsig(acc + pgen_b[0]);
}

// ---------- per-row softmax stats over V ----------
__global__ __launch_bounds__(256) void k_rowred(
    const float* __restrict__ logits,
    float* __restrict__ row_max, float* __restrict__ row_sum)
{
  int r = blockIdx.x;
  const float4* row = (const float4*)(logits + (size_t)r*VVOC);
  __shared__ float red[8];
  float m = -1e30f;
  for (int v=threadIdx.x; v<VVOC/4; v+=256){
    float4 x = row[v];
    m = fmaxf(m, fmaxf(fmaxf(x.x,x.y), fmaxf(x.z,x.w)));
  }
  m = block_max(m, red);
  float s = 0.f;
  for (int v=threadIdx.x; v<VVOC/4; v+=256){
    float4 x = row[v];
    s += __expf(x.x-m) + __expf(x.y-m) + __expf(x.z-m) + __expf(x.w-m);
  }
  s = block_sum(s, red);
  if (threadIdx.x==0){ row_max[r]=m; row_sum[r]=1.f/s; }
}

// ---------- write ext (linear domain) for all (t,b,v); t=0 row = 0 ----------
__global__ __launch_bounds__(256) void k_final(
    const float* __restrict__ logits, const float* __restrict__ pgen_all,
    const float* __restrict__ row_max, const float* __restrict__ row_sum,
    float* __restrict__ out)
{
  int v = blockIdx.x*256 + threadIdx.x;
  if (v >= VEXT) return;
  int b = blockIdx.y, t = blockIdx.z;
  size_t o = ((size_t)t*BATCH + b)*VEXT + v;
  if (t == 0){ out[o] = 0.f; return; }
  int r = (t-1)*BATCH + b;
  float val = 1e-12f;
  if (v < VVOC)
    val += pgen_all[r] * row_sum[r] * __expf(logits[(size_t)r*VVOC + v] - row_max[r]);
  out[o] = val;
}

// ---------- scatter copy-distribution ----------
__global__ __launch_bounds__(512) void k_scatter(
    const int* __restrict__ input_seq_ext,
    const float* __restrict__ alphas, const float* __restrict__ pgen_all,
    float* __restrict__ out)
{
  int r = blockIdx.x;               // t*32+b
  int s = threadIdx.x;
  if (s >= SLEN) return;
  int t = r >> 5, b = r & 31;
  float w = (1.f - pgen_all[r]) * alphas[((size_t)t*SLEN + s)*BATCH + b];
  int idx = input_seq_ext[b*SLEN + s];
  atomicAdd(&out[((size_t)(t+1)*BATCH + b)*VEXT + idx], w);
}

// ---------- log transform rows t>=1 ----------
__global__ __launch_bounds__(256) void k_log(float* __restrict__ out)
{
  int v = blockIdx.x*256 + threadIdx.x;
  if (v >= VEXT) return;
  int b = blockIdx.y, t = blockIdx.z + 1;
  size_t o = ((size_t)t*BATCH + b)*VEXT + v;
  out[o] = __logf(out[o]);
}

extern "C" void kernel_launch(void* const* d_in, const int* in_sizes, int n_in,
                              void* d_out, int out_size, void* d_ws, size_t ws_size,
                              hipStream_t stream)
{
  (void)in_sizes; (void)n_in; (void)out_size; (void)ws_size;
  const int*   input_seq     = (const int*)d_in[0];
  const int*   input_seq_ext = (const int*)d_in[1];
  const int*   target_seq    = (const int*)d_in[2];
  const float* embedding     = (const float*)d_in[3];
  const float* enc_Wih_f     = (const float*)d_in[4];
  const float* enc_Whh_f     = (const float*)d_in[5];
  const float* enc_bih_f     = (const float*)d_in[6];
  const float* enc_bhh_f     = (const float*)d_in[7];
  const float* enc_Wih_b     = (const float*)d_in[8];
  const float* enc_Whh_b     = (const float*)d_in[9];
  const float* enc_bih_b     = (const float*)d_in[10];
  const float* enc_bhh_b     = (const float*)d_in[11];
  const float* proj_W        = (const float*)d_in[12];
  const float* proj_b        = (const float*)d_in[13];
  const float* bridge_W      = (const float*)d_in[14];
  const float* bridge_b      = (const float*)d_in[15];
  const float* dec_Wih       = (const float*)d_in[16];
  const float* dec_Whh       = (const float*)d_in[17];
  const float* dec_bih       = (const float*)d_in[18];
  const float* dec_bhh       = (const float*)d_in[19];
  const float* attn_Wq       = (const float*)d_in[20];
  const float* attn_We       = (const float*)d_in[21];
  const float* lin_W         = (const float*)d_in[22];
  const float* lin_b         = (const float*)d_in[23];
  const float* pgen_W        = (const float*)d_in[24];
  const float* pgen_b        = (const float*)d_in[25];
  const float* out_W         = (const float*)d_in[26];
  const float* out_b         = (const float*)d_in[27];
  float* out = (float*)d_out;
  float* ws  = (float*)d_ws;

  // workspace layout (floats); logits overlaps dead gi_f/gi_b region
  float* emb_src    = ws;                    // 1,638,400
  float* enc_states = ws + 1638400;          // 6,553,600
  float* proj       = ws + 8192000;          // 3,276,800
  float* gi_f       = ws + 11468800;         // 9,830,400
  float* gi_b       = ws + 11468800 + 9830400;
  float* logits     = ws + 11468800;         // 24,000,000 (reuses gi region)
  float* cat_all    = ws + 35468800;         // 480*896
  float* gie_all    = ws + 35898880;         // 480*768
  float* h_dec      = ws + 36267520;         // 32*256
  float* alphas     = ws + 36275712;         // 15*400*32
  float* lin_out    = ws + 36467712;         // 480*256
  float* pgen_all   = ws + 36590592;         // 480
  float* row_max    = ws + 36591072;         // 480
  float* row_sum    = ws + 36591552;         // 480
  // total ≈ 146.4 MB

  k_embed<<<dim3(SLEN*BATCH + NDEC*BATCH), dim3(64), 0, stream>>>(
      input_seq, target_seq, embedding, emb_src, cat_all);

  // gi = emb @ Wih.T + bih, both directions (backward uses reversed source rows)
  k_gemm<<<dim3(6,100), dim3(256), 0, stream>>>(emb_src, EDIM, enc_Wih_f, EDIM, enc_bih_f, gi_f, H3, SLEN*BATCH, H3, EDIM, 0);
  k_gemm<<<dim3(6,100), dim3(256), 0, stream>>>(emb_src, EDIM, enc_Wih_b, EDIM, enc_bih_b, gi_b, H3, SLEN*BATCH, H3, EDIM, 1);

  k_enc<<<dim3(64), dim3(1024), 0, stream>>>(gi_f, gi_b, enc_Whh_f, enc_bhh_f, enc_Whh_b, enc_bhh_b, enc_states);

  // proj = enc_states @ proj_W.T + proj_b
  k_gemm<<<dim3(2,100), dim3(256), 0, stream>>>(enc_states, 2*HDIM, proj_W, 2*HDIM, proj_b, proj, HDIM, SLEN*BATCH, HDIM, 2*HDIM, 0);

  k_bridge<<<dim3(BATCH), dim3(256), 0, stream>>>(enc_states, bridge_W, bridge_b, h_dec);

  // decoder-embedding part of GRU input gates (incl. dec_bih), batched over all t
  k_gemm<<<dim3(6,4), dim3(256), 0, stream>>>(cat_all, 896, dec_Wih, 640, dec_bih, gie_all, H3, NDEC*BATCH, H3, EDIM, 0);

  for (int t=0;t<NDEC;++t)
    k_dec_step<<<dim3(BATCH), dim3(256), 0, stream>>>(t, proj, enc_states, attn_Wq, attn_We,
        dec_Wih, dec_Whh, dec_bhh, gie_all, h_dec, alphas, cat_all);

  // batched epilogue over all 15 steps
  k_gemm<<<dim3(2,4), dim3(256), 0, stream>>>(cat_all, 896, lin_W, 896, lin_b, lin_out, HDIM, NDEC*BATCH, HDIM, 896, 0);
  k_pgen<<<dim3(NDEC*BATCH), dim3(64), 0, stream>>>(cat_all, pgen_W, pgen_b, pgen_all);
  k_gemm<<<dim3(391,4), dim3(256), 0, stream>>>(lin_out, HDIM, out_W, HDIM, out_b, logits, VVOC, NDEC*BATCH, VVOC, HDIM, 0);
  k_rowred<<<dim3(NDEC*BATCH), dim3(256), 0, stream>>>(logits, row_max, row_sum);
  k_final<<<dim3(196, BATCH, TLEN), dim3(256), 0, stream>>>(logits, pgen_all, row_max, row_sum, out);
  k_scatter<<<dim3(NDEC*BATCH), dim3(512), 0, stream>>>(input_seq_ext, alphas, pgen_all, out);
  k_log<<<dim3(196, BATCH, NDEC), dim3(256), 0, stream>>>(out);
}